// Round 11
// baseline (333.977 us; speedup 1.0000x reference)
//
#include <hip/hip_runtime.h>
#include <math.h>
#include <stdint.h>

constexpr int LL = 16384;
constexpr int NROW = 65536;             // N*L
constexpr int NPAIR = NROW * 8;         // 524288 (row,head) pairs
constexpr int PAIRS_PER_N = NPAIR / 4;  // 131072
constexpr float EPS = 1e-6f;
constexpr float LN_EPS = 1e-5f;
constexpr size_t MIR_ELEMS = (size_t)NPAIR * 16;

// ---------------- workspace layout ----------------
// finals (written only by in-kernel tail reducers)
constexpr int F_KSUM = 0;               // [4][128]
constexpr int F_KN   = 512;             // [4][128]
constexpr int F_SS   = 1024;            // [4][8]
constexpr int F_QSUM = 1056;            // [4][128]
constexpr int F_QN   = 1568;            // [4][128]
constexpr int F_KV   = 2080;            // [4][2048]  (ends 10272)
// per-stage arrival counters (uint32; modulo trick -> NO zeroing needed)
constexpr int CNT_A  = 10272;           // [4]
constexpr int CNT_B  = 10276;           // [4]
constexpr int CNT_C  = 10280;           // [4]
// per-block partials (fully overwritten each run)
constexpr int P_A1 = 10304;             // [512][256] qsum|ksum per prep block
constexpr int P_A2 = P_A1 + 512 * 256;  // [512][128] qn per refq block
constexpr int P_KN = P_A2 + 512 * 128;  // [256][128] kn per kv block
constexpr int P_SS = P_KN + 256 * 128;  // [256][8]   ssum per kv block
constexpr int P_KV = P_SS + 256 * 8;    // [256][2048] KV per kv block
constexpr int FLOAT_END = P_KV + 256 * 2048;        // 766016 floats ≈ 3.06 MB
constexpr size_t MIR_Q_BYTE = (size_t)FLOAT_END * 4;
constexpr size_t MIR_K_BYTE = MIR_Q_BYTE + MIR_ELEMS * 2;
constexpr size_t WS_FULL    = MIR_K_BYTE + MIR_ELEMS * 2;   // ~36.6 MB

__device__ __forceinline__ float sigm(float x) { return __fdividef(1.f, 1.f + __expf(-x)); }
__device__ __forceinline__ unsigned short f2bf(float f) {
  uint32_t x = __float_as_uint(f);
  return (unsigned short)((x + 0x7FFFu + ((x >> 16) & 1u)) >> 16);
}
__device__ __forceinline__ float bf2f(unsigned short u) {
  return __uint_as_float(((uint32_t)u) << 16);
}

template <bool MIR>
__device__ __forceinline__ void load_sig(const unsigned short* mir, const float* fp, int p, float* r) {
  if (MIR) {
    const uint4* p4 = reinterpret_cast<const uint4*>(mir + (size_t)p * 16);
    uint4 a = p4[0], b = p4[1];
    uint32_t w[8] = {a.x, a.y, a.z, a.w, b.x, b.y, b.z, b.w};
#pragma unroll
    for (int j = 0; j < 8; ++j) {
      r[2 * j]     = bf2f((unsigned short)(w[j] & 0xFFFFu));
      r[2 * j + 1] = bf2f((unsigned short)(w[j] >> 16));
    }
  } else {
    const float4* p4 = reinterpret_cast<const float4*>(fp + (size_t)p * 16);
#pragma unroll
    for (int j = 0; j < 4; ++j) {
      float4 a = p4[j];
      r[4 * j] = sigm(a.x); r[4 * j + 1] = sigm(a.y);
      r[4 * j + 2] = sigm(a.z); r[4 * j + 3] = sigm(a.w);
    }
  }
}
__device__ __forceinline__ void load_raw16(const float* fp, int p, float* r) {
  const float4* p4 = reinterpret_cast<const float4*>(fp + (size_t)p * 16);
#pragma unroll
  for (int j = 0; j < 4; ++j) {
    float4 a = p4[j];
    r[4 * j] = a.x; r[4 * j + 1] = a.y; r[4 * j + 2] = a.z; r[4 * j + 3] = a.w;
  }
}
__device__ __forceinline__ void pack_store(unsigned short* dst, int p, const float* r) {
  union U { unsigned short u[8]; uint4 v; };
  U a, b;
#pragma unroll
  for (int j = 0; j < 8; ++j) { a.u[j] = f2bf(r[j]); b.u[j] = f2bf(r[8 + j]); }
  uint4* d = reinterpret_cast<uint4*>(dst + (size_t)p * 16);
  d[0] = a.v; d[1] = b.v;
}

// sums over the 8 lanes sharing (lane&7); every lane gets its group's sum
__device__ __forceinline__ float hred(float v) {
  v += __shfl_xor(v, 8, 64);
  v += __shfl_xor(v, 16, 64);
  v += __shfl_xor(v, 32, 64);
  return v;
}

__device__ __forceinline__ void stat_partial2(float* a, float* b, float* w4 /*[1024]*/,
                                              float* dst, int tid) {
  const int wave = tid >> 6, lane = tid & 63;
#pragma unroll
  for (int d = 0; d < 16; ++d) { a[d] = hred(a[d]); b[d] = hred(b[d]); }
  if (lane < 8) {
#pragma unroll
    for (int d = 0; d < 16; ++d) {
      w4[wave * 256 + lane * 16 + d] = a[d];
      w4[wave * 256 + 128 + lane * 16 + d] = b[d];
    }
  }
  __syncthreads();
  dst[tid] = w4[tid] + w4[256 + tid] + w4[512 + tid] + w4[768 + tid];
}

__device__ __forceinline__ void stat_partial1(float* a, float* w1 /*[512]*/,
                                              float* dst, int tid) {
  const int wave = tid >> 6, lane = tid & 63;
#pragma unroll
  for (int d = 0; d < 16; ++d) a[d] = hred(a[d]);
  if (lane < 8) {
#pragma unroll
    for (int d = 0; d < 16; ++d) w1[wave * 128 + lane * 16 + d] = a[d];
  }
  __syncthreads();
  if (tid < 128) dst[tid] = w1[tid] + w1[128 + tid] + w1[256 + tid] + w1[384 + tid];
}

// last-block election (threadFenceReduction pattern, poison-proof via modulo):
// all threads: release-fence own stores -> sync -> tid0 bumps counter; the block
// observing (old+1)%TARGET==0 is last; it acquire-fences before reading partials.
template <unsigned int TARGET>
__device__ __forceinline__ bool last_block(unsigned int* cnt, int tid, unsigned int* flag) {
  __threadfence();
  __syncthreads();
  if (tid == 0) {
    const unsigned int old = atomicAdd(cnt, 1u);
    *flag = (((old + 1u) & (TARGET - 1u)) == 0u) ? 1u : 0u;
  }
  __syncthreads();
  const bool last = (*flag != 0u);
  if (last) __threadfence();
  return last;
}

// Pass 1: sigmoid, bf16 mirrors, qsum/ksum partials + in-kernel tail reduce.
// 512 blocks (128/n) x 4 chunks — r3-proven body.
template <bool MIR>
__global__ __launch_bounds__(256) void k_prep(const float* __restrict__ Q, const float* __restrict__ K,
                                              float* __restrict__ ws,
                                              unsigned short* __restrict__ sQ, unsigned short* __restrict__ sK) {
  const int tid = threadIdx.x;
  const int n = blockIdx.x >> 7;       // 128 blocks per n
  const int b = blockIdx.x & 127;
  __shared__ float w4[1024];
  __shared__ unsigned int flag;
  float sq[16], sk[16];
#pragma unroll
  for (int d = 0; d < 16; ++d) { sq[d] = 0.f; sk[d] = 0.f; }
#pragma unroll
  for (int c = 0; c < 4; ++c) {
    const int p = n * PAIRS_PER_N + (b * 4 + c) * 256 + tid;
    float q[16], k[16];
    load_sig<false>(nullptr, Q, p, q);
    load_sig<false>(nullptr, K, p, k);
    if (MIR) { pack_store(sQ, p, q); pack_store(sK, p, k); }
#pragma unroll
    for (int d = 0; d < 16; ++d) { sq[d] += q[d]; sk[d] += k[d]; }
  }
  stat_partial2(sq, sk, w4, ws + P_A1 + (size_t)blockIdx.x * 256, tid);
  // tail: last of the 128 blocks for this n reduces 128x256 -> F_QSUM|F_KSUM
  unsigned int* cnt = reinterpret_cast<unsigned int*>(ws) + CNT_A + n;
  if (last_block<128u>(cnt, tid, &flag)) {
    float acc = 0.f;
    const float* src = ws + P_A1 + (size_t)n * 128 * 256 + tid;
#pragma unroll 8
    for (int c = 0; c < 128; ++c) acc += src[(size_t)c * 256];
    if (tid < 128) ws[F_QSUM + n * 128 + tid] = acc;
    else ws[F_KSUM + n * 128 + (tid - 128)] = acc;
  }
}

// Pass 2: qn = sum_l q*nr partials + tail reduce. 512 blocks x 4 chunks.
template <bool MIR>
__global__ __launch_bounds__(256) void k_refq(const float* __restrict__ Q,
                                              const unsigned short* __restrict__ sQ,
                                              float* __restrict__ ws) {
  const int tid = threadIdx.x;
  const int n = blockIdx.x >> 7;
  const int b = blockIdx.x & 127;
  __shared__ float ksE[128];
  __shared__ float w1[512];
  __shared__ unsigned int flag;
  if (tid < 128) ksE[tid] = ws[F_KSUM + n * 128 + tid] + EPS;
  __syncthreads();
  const int h = tid & 7;
  float qn[16];
#pragma unroll
  for (int d = 0; d < 16; ++d) qn[d] = 0.f;
#pragma unroll
  for (int c = 0; c < 4; ++c) {
    const int p = n * PAIRS_PER_N + (b * 4 + c) * 256 + tid;
    float q[16];
    load_sig<MIR>(sQ, Q, p, q);
    float dr = 0.f;
#pragma unroll
    for (int d = 0; d < 16; ++d) dr += (q[d] + EPS) * ksE[h * 16 + d];
    const float nr = __fdividef(1.f, dr);
#pragma unroll
    for (int d = 0; d < 16; ++d) qn[d] += q[d] * nr;
  }
  stat_partial1(qn, w1, ws + P_A2 + (size_t)blockIdx.x * 128, tid);
  // tail: split depth 128 across two half-blocks (deterministic lo+hi order)
  unsigned int* cnt = reinterpret_cast<unsigned int*>(ws) + CNT_B + n;
  if (last_block<128u>(cnt, tid, &flag)) {
    const int col = tid & 127, half = tid >> 7;    // half 0: c=0..63, half 1: c=64..127
    float acc = 0.f;
    const float* src = ws + P_A2 + (size_t)(n * 128 + half * 64) * 128 + col;
#pragma unroll 8
    for (int c = 0; c < 64; ++c) acc += src[(size_t)c * 128];
    if (half) w1[col] = acc;
    __syncthreads();
    if (!half) ws[F_QN + n * 128 + col] = acc + w1[col];
  }
}

// Pass 3: nc/kn, w = exp(k.qnE), ssum, weighted-KV tile partials + tail reduce.
// 256 blocks (64/n) x 8 tiles of 32 rows, register double-buffer — r3-proven body.
template <bool MIR>
__global__ __launch_bounds__(256) void k_kv(const float* __restrict__ K, const float* __restrict__ V,
                                            const unsigned short* __restrict__ sK,
                                            float* __restrict__ ws) {
  const int tid = threadIdx.x;
  const int n = blockIdx.x >> 6;       // 64 blocks per n
  const int b = blockIdx.x & 63;
  constexpr int RS = 132;              // row stride: head-stride 16 (aligned wide reads), +4 pad
  __shared__ float qnE[128], qsE[128];
  __shared__ float ssb[8];
  __shared__ float w1[512];
  __shared__ __align__(16) float kwL[32 * RS];
  __shared__ __align__(16) float vL[32 * RS];
  __shared__ unsigned int flag;
  if (tid < 128) {
    qnE[tid] = ws[F_QN + n * 128 + tid] + EPS;
    qsE[tid] = ws[F_QSUM + n * 128 + tid] + EPS;
  }
  if (tid < 8) ssb[tid] = 0.f;
  __syncthreads();
  const int h = tid & 7, ri = tid >> 3, lane = tid & 63;
  const int h2 = tid >> 5;
  const int d0 = ((tid >> 2) & 7) * 2;
  const int e0 = (tid & 3) * 4;
  const int base = n * PAIRS_PER_N + b * 2048;   // 8 tiles x 256 pairs
  float acc[2][4] = {{0.f, 0.f, 0.f, 0.f}, {0.f, 0.f, 0.f, 0.f}};
  float kn[16];
#pragma unroll
  for (int d = 0; d < 16; ++d) kn[d] = 0.f;
  float kb[2][16], vb[2][16];
  load_sig<MIR>(sK, K, base + tid, kb[0]);
  load_raw16(V, base + tid, vb[0]);
#pragma unroll 2
  for (int t = 0; t < 8; ++t) {
    const int cur = t & 1, nxt = cur ^ 1;
    float* k = kb[cur];
    float* v = vb[cur];
    float dc = 0.f, ncr = 0.f;
#pragma unroll
    for (int d = 0; d < 16; ++d) {
      const float ke = k[d] + EPS;
      dc += ke * qsE[h * 16 + d];
      ncr += ke * qnE[h * 16 + d];
    }
    const float nc = __fdividef(1.f, dc);
#pragma unroll
    for (int d = 0; d < 16; ++d) kn[d] += k[d] * nc;
    const float w = __expf(ncr);   // ncr is O(1): no max-subtraction needed
    float sw = hred(w);
    if (lane < 8) atomicAdd(&ssb[lane], sw);   // LDS atomic, 8 addresses
    const int wb = ri * RS + h * 16;
#pragma unroll
    for (int d = 0; d < 16; ++d) { kwL[wb + d] = k[d] * w; vL[wb + d] = v[d]; }
    // prefetch next tile before the barrier; loads stay in flight across it
    if (t < 7) {
      load_sig<MIR>(sK, K, base + (t + 1) * 256 + tid, kb[nxt]);
      load_raw16(V, base + (t + 1) * 256 + tid, vb[nxt]);
    }
    __syncthreads();
    const int rb0 = h2 * 16;
#pragma unroll 4
    for (int r = 0; r < 32; ++r) {
      const int rb = r * RS + rb0;
      const float2 kk = *reinterpret_cast<const float2*>(&kwL[rb + d0]);
      const float4 vv = *reinterpret_cast<const float4*>(&vL[rb + e0]);
      acc[0][0] += kk.x * vv.x; acc[0][1] += kk.x * vv.y;
      acc[0][2] += kk.x * vv.z; acc[0][3] += kk.x * vv.w;
      acc[1][0] += kk.y * vv.x; acc[1][1] += kk.y * vv.y;
      acc[1][2] += kk.y * vv.z; acc[1][3] += kk.y * vv.w;
    }
    __syncthreads();
  }
  // per-block partial writes (deterministic)
  stat_partial1(kn, w1, ws + P_KN + (size_t)blockIdx.x * 128, tid);
  if (tid < 8) ws[P_SS + (size_t)blockIdx.x * 8 + tid] = ssb[tid];
  float* pk = ws + P_KV + (size_t)blockIdx.x * 2048;
  *reinterpret_cast<float4*>(pk + h2 * 256 + d0 * 16 + e0) =
      make_float4(acc[0][0], acc[0][1], acc[0][2], acc[0][3]);
  *reinterpret_cast<float4*>(pk + h2 * 256 + (d0 + 1) * 16 + e0) =
      make_float4(acc[1][0], acc[1][1], acc[1][2], acc[1][3]);
  // tail: last of the 64 blocks for this n reduces KV (8 cols/thread), kn, ssum
  unsigned int* cnt = reinterpret_cast<unsigned int*>(ws) + CNT_C + n;
  if (last_block<64u>(cnt, tid, &flag)) {
    float a8[8];
#pragma unroll
    for (int j = 0; j < 8; ++j) a8[j] = 0.f;
    const float* srcKV = ws + P_KV + (size_t)n * 64 * 2048;
#pragma unroll 2
    for (int c = 0; c < 64; ++c) {
      const float* s = srcKV + (size_t)c * 2048 + tid;
#pragma unroll
      for (int j = 0; j < 8; ++j) a8[j] += s[j * 256];
    }
#pragma unroll
    for (int j = 0; j < 8; ++j) ws[F_KV + n * 2048 + j * 256 + tid] = a8[j];
    if (tid < 128) {
      float a = 0.f;
      const float* s = ws + P_KN + (size_t)n * 64 * 128 + tid;
#pragma unroll 8
      for (int c = 0; c < 64; ++c) a += s[(size_t)c * 128];
      ws[F_KN + n * 128 + tid] = a;
    }
    if (tid < 8) {
      float a = 0.f;
      const float* s = ws + P_SS + (size_t)n * 64 * 8 + tid;
#pragma unroll 8
      for (int c = 0; c < 64; ++c) a += s[(size_t)c * 8];
      ws[F_SS + n * 8 + tid] = a;
    }
  }
}

// Pass 4: x = q@kv * nr*nrr + v, LayerNorm, write out. Reads finals only.
template <bool MIR>
__global__ __launch_bounds__(256) void k_out(const float* __restrict__ Q, const float* __restrict__ V,
                                             const unsigned short* __restrict__ sQ,
                                             const float* __restrict__ gamma, const float* __restrict__ beta,
                                             const float* __restrict__ ws, float* __restrict__ out) {
  const int tid = threadIdx.x;
  const int p = blockIdx.x * 256 + tid;
  const int n = blockIdx.x >> 9;
  __shared__ __align__(16) float kvs[8 * 260];  // pad 260 → conflict-free by h
  __shared__ float ksE[128], knE[128], gm[16], bt[16], ssE[8];
  if (tid < 8) ssE[tid] = __fdividef((float)LL, ws[F_SS + n * 8 + tid]);
  if (tid >= 8 && tid < 136) {
    const int i = tid - 8;
    ksE[i] = ws[F_KSUM + n * 128 + i] + EPS;
    knE[i] = ws[F_KN + n * 128 + i] + EPS;
  }
  if (tid >= 136 && tid < 152) gm[tid - 136] = gamma[tid - 136];
  else if (tid >= 152 && tid < 168) bt[tid - 152] = beta[tid - 152];
  __syncthreads();
  for (int i = tid; i < 2048; i += 256) {
    const int hh = i >> 8, de = i & 255;
    kvs[hh * 260 + de] = ws[F_KV + n * 2048 + i] * ssE[hh];
  }
  __syncthreads();
  const int h = tid & 7;
  float q[16], v[16];
  load_sig<MIR>(sQ, Q, p, q);
  load_raw16(V, p, v);
  float dr = 0.f, drr = 0.f;
#pragma unroll
  for (int d = 0; d < 16; ++d) {
    const float qe = q[d] + EPS;
    dr += qe * ksE[h * 16 + d];
    drr += qe * knE[h * 16 + d];
  }
  const float sc = __fdividef(1.f, dr) * sigm(drr);
  float x[16];
#pragma unroll
  for (int e = 0; e < 16; ++e) x[e] = 0.f;
#pragma unroll
  for (int d = 0; d < 16; ++d) {
    const float qd = q[d];
    const float4* kr = reinterpret_cast<const float4*>(&kvs[h * 260 + d * 16]);
#pragma unroll
    for (int j = 0; j < 4; ++j) {
      float4 a = kr[j];
      x[4 * j] += qd * a.x; x[4 * j + 1] += qd * a.y;
      x[4 * j + 2] += qd * a.z; x[4 * j + 3] += qd * a.w;
    }
  }
#pragma unroll
  for (int e = 0; e < 16; ++e) x[e] = x[e] * sc + v[e];
  float mean = 0.f;
#pragma unroll
  for (int e = 0; e < 16; ++e) mean += x[e];
  mean *= (1.f / 16.f);
  float var = 0.f;
#pragma unroll
  for (int e = 0; e < 16; ++e) { const float t = x[e] - mean; var += t * t; }
  var *= (1.f / 16.f);
  const float inv = rsqrtf(var + LN_EPS);
#pragma unroll
  for (int e = 0; e < 16; ++e) x[e] = (x[e] - mean) * inv * gm[e] + bt[e];
  float4* op = reinterpret_cast<float4*>(out + (size_t)p * 16);
  op[0] = make_float4(x[0], x[1], x[2], x[3]);
  op[1] = make_float4(x[4], x[5], x[6], x[7]);
  op[2] = make_float4(x[8], x[9], x[10], x[11]);
  op[3] = make_float4(x[12], x[13], x[14], x[15]);
}

extern "C" void kernel_launch(void* const* d_in, const int* in_sizes, int n_in,
                              void* d_out, int out_size, void* d_ws, size_t ws_size,
                              hipStream_t stream) {
  const float* Q = (const float*)d_in[0];
  const float* K = (const float*)d_in[1];
  const float* V = (const float*)d_in[2];
  const float* gamma = (const float*)d_in[3];
  const float* beta = (const float*)d_in[4];
  float* ws = (float*)d_ws;
  float* out = (float*)d_out;
  unsigned short* sQ = (unsigned short*)((char*)d_ws + MIR_Q_BYTE);
  unsigned short* sK = (unsigned short*)((char*)d_ws + MIR_K_BYTE);

  const dim3 blk(256);
  const int gPrep = 512;               // 128 blocks/n x 4 chunks
  const int gKv = 256;                 // 64 blocks/n x 8 tiles
  const int gOut = NPAIR / 256;        // 2048

  if (ws_size >= WS_FULL) {
    k_prep<true><<<gPrep, blk, 0, stream>>>(Q, K, ws, sQ, sK);
    k_refq<true><<<gPrep, blk, 0, stream>>>(Q, sQ, ws);
    k_kv<true><<<gKv, blk, 0, stream>>>(K, V, sK, ws);
    k_out<true><<<gOut, blk, 0, stream>>>(Q, V, sQ, gamma, beta, ws, out);
  } else {
    k_prep<false><<<gPrep, blk, 0, stream>>>(Q, K, ws, nullptr, nullptr);
    k_refq<false><<<gPrep, blk, 0, stream>>>(Q, nullptr, ws);
    k_kv<false><<<gKv, blk, 0, stream>>>(K, V, nullptr, ws);
    k_out<false><<<gOut, blk, 0, stream>>>(Q, V, nullptr, gamma, beta, ws, out);
  }
}